// Round 1
// baseline (106.122 us; speedup 1.0000x reference)
//
#include <hip/hip_runtime.h>

#define HH 1024
#define WW 1024
#define NIMG 8

__device__ __forceinline__ void ce(float& a, float& b) {
    float lo = fminf(a, b);
    float hi = fmaxf(a, b);
    a = lo; b = hi;
}

// min-max pass: places min of w[0..S-1] at w[0], max at w[S-1]; multiset preserved.
template<int S>
__device__ __forceinline__ void mmpass(float* w) {
    #pragma unroll
    for (int i = 0; i + 1 < S; i += 2) ce(w[i], w[i + 1]);
    #pragma unroll
    for (int i = 2; i < S; i += 2) ce(w[0], w[i]);        // evens (+leftover if S odd)
    #pragma unroll
    for (int i = 1; i < S - 1; i += 2) ce(w[i], w[S - 1]); // odds -> w[S-1]
}

// Forgetful selection: set of size S, discard min&max, insert v[next], recurse.
template<int S>
struct Forget {
    __device__ __forceinline__ static float run(float* w, const float* v, int next) {
        mmpass<S>(w);
        #pragma unroll
        for (int i = 0; i < S - 2; i++) w[i] = w[i + 1];
        w[S - 2] = v[next];
        return Forget<S - 1>::run(w, v, next + 1);
    }
};
template<>
struct Forget<3> {
    __device__ __forceinline__ static float run(float* w, const float*, int) {
        mmpass<3>(w);
        return w[1];
    }
};

__device__ __forceinline__ float median25(const float* v) {
    float w[14];
    #pragma unroll
    for (int i = 0; i < 14; i++) w[i] = v[i];
    return Forget<14>::run(w, v, 14);
}

__device__ __forceinline__ int reflect_idx(int i, int n) {
    // np.pad mode='reflect': -1 -> 1, -2 -> 2, n -> n-2, n+1 -> n-3
    if (i < 0) return -i;
    if (i >= n) return 2 * n - 2 - i;
    return i;
}

// Block = one image row (gridDim.x = NIMG*HH). Thread t handles 4 pixels x0=4t..4t+3.
__global__ __launch_bounds__(256) void median_kernel(const float* __restrict__ in,
                                                     float* __restrict__ out) {
    const int bi  = blockIdx.x;
    const int img = bi >> 10;
    const int y   = bi & (HH - 1);
    const int tid = threadIdx.x;
    const int x0  = tid * 4;
    const float* base = in + (size_t)img * HH * WW;

    float patch[5][8];
    const bool interior = (tid != 0) && (tid != 255);
    #pragma unroll
    for (int r = 0; r < 5; r++) {
        const int yy = reflect_idx(y + r - 2, HH);
        const float* rp = base + (size_t)yy * WW;
        if (interior) {
            const float2 a = *reinterpret_cast<const float2*>(rp + x0 - 2);
            const float2 b = *reinterpret_cast<const float2*>(rp + x0);
            const float2 c = *reinterpret_cast<const float2*>(rp + x0 + 2);
            const float2 d = *reinterpret_cast<const float2*>(rp + x0 + 4);
            patch[r][0] = a.x; patch[r][1] = a.y;
            patch[r][2] = b.x; patch[r][3] = b.y;
            patch[r][4] = c.x; patch[r][5] = c.y;
            patch[r][6] = d.x; patch[r][7] = d.y;
        } else {
            #pragma unroll
            for (int c = 0; c < 8; c++) {
                const int xx = reflect_idx(x0 + c - 2, WW);
                patch[r][c] = rp[xx];
            }
        }
    }

    float med[4];
    #pragma unroll
    for (int j = 0; j < 4; j++) {
        float v[25];
        #pragma unroll
        for (int r = 0; r < 5; r++)
            #pragma unroll
            for (int c = 0; c < 5; c++)
                v[r * 5 + c] = patch[r][j + c];
        med[j] = median25(v);
    }

    float4 o;
    o.x = med[0]; o.y = med[1]; o.z = med[2]; o.w = med[3];
    *reinterpret_cast<float4*>(out + (size_t)img * HH * WW + (size_t)y * WW + x0) = o;
}

// Gaussian 5x5, zero padding, separable weights computed from runtime sigma.
__global__ __launch_bounds__(256) void gauss_kernel(const float* __restrict__ in,
                                                    const float* __restrict__ sig,
                                                    float* __restrict__ out) {
    const int bi  = blockIdx.x;
    const int img = bi >> 10;
    const int y   = bi & (HH - 1);
    const int tid = threadIdx.x;
    const int x0  = tid * 4;

    const float sigma  = sig[0];
    const float inv2s2 = 1.0f / (2.0f * sigma * sigma);
    const float g1 = expf(-1.0f * inv2s2);
    const float g4 = expf(-4.0f * inv2s2);
    const float s  = 1.0f + 2.0f * g1 + 2.0f * g4;
    float wv[5];
    wv[0] = g4 / s; wv[1] = g1 / s; wv[2] = 1.0f / s; wv[3] = g1 / s; wv[4] = g4 / s;

    const float* base = in + (size_t)img * HH * WW;
    const bool interior = (tid != 0) && (tid != 255);

    float acc0 = 0.f, acc1 = 0.f, acc2 = 0.f, acc3 = 0.f;
    #pragma unroll
    for (int r = 0; r < 5; r++) {
        const int yy = y + r - 2;
        if (yy < 0 || yy >= HH) continue;  // zero padding
        const float* rp = base + (size_t)yy * WW;
        float row[8];
        if (interior) {
            const float2 a = *reinterpret_cast<const float2*>(rp + x0 - 2);
            const float2 b = *reinterpret_cast<const float2*>(rp + x0);
            const float2 c = *reinterpret_cast<const float2*>(rp + x0 + 2);
            const float2 d = *reinterpret_cast<const float2*>(rp + x0 + 4);
            row[0] = a.x; row[1] = a.y; row[2] = b.x; row[3] = b.y;
            row[4] = c.x; row[5] = c.y; row[6] = d.x; row[7] = d.y;
        } else {
            #pragma unroll
            for (int c = 0; c < 8; c++) {
                const int xx = x0 + c - 2;
                row[c] = (xx < 0 || xx >= WW) ? 0.0f : rp[xx];
            }
        }
        float h0 = 0.f, h1 = 0.f, h2 = 0.f, h3 = 0.f;
        #pragma unroll
        for (int c = 0; c < 5; c++) {
            h0 = fmaf(wv[c], row[0 + c], h0);
            h1 = fmaf(wv[c], row[1 + c], h1);
            h2 = fmaf(wv[c], row[2 + c], h2);
            h3 = fmaf(wv[c], row[3 + c], h3);
        }
        const float wy = wv[r];
        acc0 = fmaf(wy, h0, acc0);
        acc1 = fmaf(wy, h1, acc1);
        acc2 = fmaf(wy, h2, acc2);
        acc3 = fmaf(wy, h3, acc3);
    }

    float4 o;
    o.x = acc0; o.y = acc1; o.z = acc2; o.w = acc3;
    *reinterpret_cast<float4*>(out + (size_t)img * HH * WW + (size_t)y * WW + x0) = o;
}

extern "C" void kernel_launch(void* const* d_in, const int* in_sizes, int n_in,
                              void* d_out, int out_size, void* d_ws, size_t ws_size,
                              hipStream_t stream) {
    const float* img = (const float*)d_in[0];
    const float* sig = (const float*)d_in[1];
    float* med = (float*)d_ws;
    float* out = (float*)d_out;

    dim3 grid(NIMG * HH);
    dim3 block(256);
    hipLaunchKernelGGL(median_kernel, grid, block, 0, stream, img, med);
    hipLaunchKernelGGL(gauss_kernel, grid, block, 0, stream, med, sig, out);
}

// Round 2
// 89.017 us; speedup vs baseline: 1.1921x; 1.1921x over previous
//
#include <hip/hip_runtime.h>

#define HH 1024
#define WW 1024
#define NIMG 8

__device__ __forceinline__ float med3f(float a, float b, float c) {
    return __builtin_amdgcn_fmed3f(a, b, c);
}
__device__ __forceinline__ float min3f(float a, float b, float c) {
    return fminf(fminf(a, b), c);
}
__device__ __forceinline__ float max3f(float a, float b, float c) {
    return fmaxf(fmaxf(a, b), c);
}

__device__ __forceinline__ void ce(float& a, float& b) {
    float lo = fminf(a, b);
    float hi = fmaxf(a, b);
    a = lo; b = hi;
}

// min-max pass: places min of w[0..S-1] at w[0], max at w[S-1]; multiset preserved.
template<int S>
__device__ __forceinline__ void mmpass(float* w) {
    #pragma unroll
    for (int i = 0; i + 1 < S; i += 2) ce(w[i], w[i + 1]);
    #pragma unroll
    for (int i = 2; i < S; i += 2) ce(w[0], w[i]);
    #pragma unroll
    for (int i = 1; i < S - 1; i += 2) ce(w[i], w[S - 1]);
}

// Forgetful selection over 13 elements, rank 7 (median). Start size 8.
// Invariant S + k_discarded_pairs = 8: discarded min always has >=7 guaranteed
// above (S-1 in W + k prior maxes), so rank <= 6 < 7; symmetric for max.
template<int S>
struct Forget {
    __device__ __forceinline__ static float run(float* w, const float* v, int next) {
        mmpass<S>(w);
        #pragma unroll
        for (int i = 0; i < S - 2; i++) w[i] = w[i + 1];
        w[S - 2] = v[next];
        return Forget<S - 1>::run(w, v, next + 1);
    }
};
template<>
struct Forget<3> {
    __device__ __forceinline__ static float run(float* w, const float*, int) {
        return med3f(w[0], w[1], w[2]);
    }
};

// In-place ascending sort of 5 values using min3/med3/max3 insertion identities.
__device__ __forceinline__ void sort5(float& a, float& b, float& c, float& d, float& e) {
    // sort3(a,b,c)
    float l3 = min3f(a, b, c);
    float m3 = med3f(a, b, c);
    float h3 = max3f(a, b, c);
    // insert d -> sorted4
    float s0 = fminf(l3, d);
    float s1 = med3f(l3, m3, d);
    float s2 = med3f(m3, h3, d);
    float s3 = fmaxf(h3, d);
    // insert e -> sorted5
    float r0 = fminf(s0, e);
    float r1 = med3f(s0, s1, e);
    float r2 = med3f(s1, s2, e);
    float r3 = med3f(s2, s3, e);
    float r4 = fmaxf(s3, e);
    a = r0; b = r1; c = r2; d = r3; e = r4;
}

__device__ __forceinline__ int reflect_idx(int i, int n) {
    if (i < 0) return -i;
    if (i >= n) return 2 * n - 2 - i;
    return i;
}

// Block = one image row. Thread t handles 4 pixels x0=4t..4t+3.
// Median via: shared sorted columns (8 per thread) -> per-window row sort
// (doubly-monotone 5x5) -> 13-candidate pruning -> forgetful-8.
__global__ __launch_bounds__(256) void median_kernel(const float* __restrict__ in,
                                                     float* __restrict__ out) {
    const int bi  = blockIdx.x;
    const int img = bi >> 10;
    const int y   = bi & (HH - 1);
    const int tid = threadIdx.x;
    const int x0  = tid * 4;
    const float* base = in + (size_t)img * HH * WW;

    float patch[5][8];
    const bool interior = (tid != 0) && (tid != 255);
    #pragma unroll
    for (int r = 0; r < 5; r++) {
        const int yy = reflect_idx(y + r - 2, HH);
        const float* rp = base + (size_t)yy * WW;
        if (interior) {
            const float2 a = *reinterpret_cast<const float2*>(rp + x0 - 2);
            const float2 b = *reinterpret_cast<const float2*>(rp + x0);
            const float2 c = *reinterpret_cast<const float2*>(rp + x0 + 2);
            const float2 d = *reinterpret_cast<const float2*>(rp + x0 + 4);
            patch[r][0] = a.x; patch[r][1] = a.y;
            patch[r][2] = b.x; patch[r][3] = b.y;
            patch[r][4] = c.x; patch[r][5] = c.y;
            patch[r][6] = d.x; patch[r][7] = d.y;
        } else {
            #pragma unroll
            for (int c = 0; c < 8; c++) {
                const int xx = reflect_idx(x0 + c - 2, WW);
                patch[r][c] = rp[xx];
            }
        }
    }

    // Sort each of the 8 columns (shared by the 4 windows).
    #pragma unroll
    for (int c = 0; c < 8; c++) {
        sort5(patch[0][c], patch[1][c], patch[2][c], patch[3][c], patch[4][c]);
    }

    float med[4];
    #pragma unroll
    for (int j = 0; j < 4; j++) {
        // Row-sort the 5x5 (rows = same rank across the window's 5 sorted
        // columns). Row sorting preserves column order -> doubly monotone.
        float R[5][5];
        #pragma unroll
        for (int i = 0; i < 5; i++) {
            float a = patch[i][j + 0];
            float b = patch[i][j + 1];
            float c = patch[i][j + 2];
            float d = patch[i][j + 3];
            float e = patch[i][j + 4];
            sort5(a, b, c, d, e);
            R[i][0] = a; R[i][1] = b; R[i][2] = c; R[i][3] = d; R[i][4] = e;
        }
        // Doubly-monotone rank pruning: cell (i,j) has (i+1)(j+1)-1 elements
        // guaranteed <= and (5-i)(5-j)-1 guaranteed >=. 12 cells provably not
        // the median; 13 candidates remain, median25 = median of these 13.
        float w[8] = { R[0][3], R[0][4], R[1][2], R[1][3],
                       R[1][4], R[2][1], R[2][2], R[2][3] };
        float ins[5] = { R[3][0], R[3][1], R[3][2], R[4][0], R[4][1] };
        med[j] = Forget<8>::run(w, ins, 0);
    }

    float4 o;
    o.x = med[0]; o.y = med[1]; o.z = med[2]; o.w = med[3];
    *reinterpret_cast<float4*>(out + (size_t)img * HH * WW + (size_t)y * WW + x0) = o;
}

// Gaussian 5x5, zero padding, separable weights computed from runtime sigma.
__global__ __launch_bounds__(256) void gauss_kernel(const float* __restrict__ in,
                                                    const float* __restrict__ sig,
                                                    float* __restrict__ out) {
    const int bi  = blockIdx.x;
    const int img = bi >> 10;
    const int y   = bi & (HH - 1);
    const int tid = threadIdx.x;
    const int x0  = tid * 4;

    const float sigma  = sig[0];
    const float inv2s2 = 1.0f / (2.0f * sigma * sigma);
    const float g1 = expf(-1.0f * inv2s2);
    const float g4 = expf(-4.0f * inv2s2);
    const float s  = 1.0f + 2.0f * g1 + 2.0f * g4;
    float wv[5];
    wv[0] = g4 / s; wv[1] = g1 / s; wv[2] = 1.0f / s; wv[3] = g1 / s; wv[4] = g4 / s;

    const float* base = in + (size_t)img * HH * WW;
    const bool interior = (tid != 0) && (tid != 255);

    float acc0 = 0.f, acc1 = 0.f, acc2 = 0.f, acc3 = 0.f;
    #pragma unroll
    for (int r = 0; r < 5; r++) {
        const int yy = y + r - 2;
        if (yy < 0 || yy >= HH) continue;  // zero padding
        const float* rp = base + (size_t)yy * WW;
        float row[8];
        if (interior) {
            const float2 a = *reinterpret_cast<const float2*>(rp + x0 - 2);
            const float2 b = *reinterpret_cast<const float2*>(rp + x0);
            const float2 c = *reinterpret_cast<const float2*>(rp + x0 + 2);
            const float2 d = *reinterpret_cast<const float2*>(rp + x0 + 4);
            row[0] = a.x; row[1] = a.y; row[2] = b.x; row[3] = b.y;
            row[4] = c.x; row[5] = c.y; row[6] = d.x; row[7] = d.y;
        } else {
            #pragma unroll
            for (int c = 0; c < 8; c++) {
                const int xx = x0 + c - 2;
                row[c] = (xx < 0 || xx >= WW) ? 0.0f : rp[xx];
            }
        }
        float h0 = 0.f, h1 = 0.f, h2 = 0.f, h3 = 0.f;
        #pragma unroll
        for (int c = 0; c < 5; c++) {
            h0 = fmaf(wv[c], row[0 + c], h0);
            h1 = fmaf(wv[c], row[1 + c], h1);
            h2 = fmaf(wv[c], row[2 + c], h2);
            h3 = fmaf(wv[c], row[3 + c], h3);
        }
        const float wy = wv[r];
        acc0 = fmaf(wy, h0, acc0);
        acc1 = fmaf(wy, h1, acc1);
        acc2 = fmaf(wy, h2, acc2);
        acc3 = fmaf(wy, h3, acc3);
    }

    float4 o;
    o.x = acc0; o.y = acc1; o.z = acc2; o.w = acc3;
    *reinterpret_cast<float4*>(out + (size_t)img * HH * WW + (size_t)y * WW + x0) = o;
}

extern "C" void kernel_launch(void* const* d_in, const int* in_sizes, int n_in,
                              void* d_out, int out_size, void* d_ws, size_t ws_size,
                              hipStream_t stream) {
    const float* img = (const float*)d_in[0];
    const float* sig = (const float*)d_in[1];
    float* med = (float*)d_ws;
    float* out = (float*)d_out;

    dim3 grid(NIMG * HH);
    dim3 block(256);
    hipLaunchKernelGGL(median_kernel, grid, block, 0, stream, img, med);
    hipLaunchKernelGGL(gauss_kernel, grid, block, 0, stream, med, sig, out);
}

// Round 3
// 78.299 us; speedup vs baseline: 1.3553x; 1.1369x over previous
//
#include <hip/hip_runtime.h>

#define HH 1024
#define WW 1024
#define NIMG 8

__device__ __forceinline__ float med3f(float a, float b, float c) {
    return __builtin_amdgcn_fmed3f(a, b, c);
}
__device__ __forceinline__ float min3f(float a, float b, float c) {
    return fminf(fminf(a, b), c);
}
__device__ __forceinline__ float max3f(float a, float b, float c) {
    return fmaxf(fmaxf(a, b), c);
}

// Full ascending sort5 (12 ops) — used for columns (all ranks needed).
__device__ __forceinline__ void sort5(float& a, float& b, float& c, float& d, float& e) {
    float l3 = min3f(a, b, c);
    float m3 = med3f(a, b, c);
    float h3 = max3f(a, b, c);
    float s0 = fminf(l3, d);
    float s1 = med3f(l3, m3, d);
    float s2 = med3f(m3, h3, d);
    float s3 = fmaxf(h3, d);
    float r0 = fminf(s0, e);
    float r1 = med3f(s0, s1, e);
    float r2 = med3f(s1, s2, e);
    float r3 = med3f(s2, s3, e);
    float r4 = fmaxf(s3, e);
    a = r0; b = r1; c = r2; d = r3; e = r4;
}

// ranks 3,4 of 5 (6 ops)
__device__ __forceinline__ void top2(float a, float b, float c, float d, float e,
                                     float& r3, float& r4) {
    float m3 = med3f(a, b, c);
    float h3 = max3f(a, b, c);
    float s2 = med3f(m3, h3, d);
    float s3 = fmaxf(h3, d);
    r3 = med3f(s2, s3, e);
    r4 = fmaxf(s3, e);
}
// ranks 0,1 of 5 (6 ops)
__device__ __forceinline__ void bot2(float a, float b, float c, float d, float e,
                                     float& r0, float& r1) {
    float l3 = min3f(a, b, c);
    float m3 = med3f(a, b, c);
    float s0 = fminf(l3, d);
    float s1 = med3f(l3, m3, d);
    r0 = fminf(s0, e);
    r1 = med3f(s0, s1, e);
}
// ranks 2,3,4 of 5 (9 ops)
__device__ __forceinline__ void top3(float a, float b, float c, float d, float e,
                                     float& r2, float& r3, float& r4) {
    float l3 = min3f(a, b, c);
    float m3 = med3f(a, b, c);
    float h3 = max3f(a, b, c);
    float s1 = med3f(l3, m3, d);
    float s2 = med3f(m3, h3, d);
    float s3 = fmaxf(h3, d);
    r2 = med3f(s1, s2, e);
    r3 = med3f(s2, s3, e);
    r4 = fmaxf(s3, e);
}
// ranks 0,1,2 of 5 (9 ops)
__device__ __forceinline__ void bot3(float a, float b, float c, float d, float e,
                                     float& r0, float& r1, float& r2) {
    float l3 = min3f(a, b, c);
    float m3 = med3f(a, b, c);
    float h3 = max3f(a, b, c);
    float s0 = fminf(l3, d);
    float s1 = med3f(l3, m3, d);
    float s2 = med3f(m3, h3, d);
    r0 = fminf(s0, e);
    r1 = med3f(s0, s1, e);
    r2 = med3f(s1, s2, e);
}
// ranks 1,2,3 of 5 (10 ops)
__device__ __forceinline__ void mid3(float a, float b, float c, float d, float e,
                                     float& r1, float& r2, float& r3) {
    float l3 = min3f(a, b, c);
    float m3 = med3f(a, b, c);
    float h3 = max3f(a, b, c);
    float s0 = fminf(l3, d);
    float s1 = med3f(l3, m3, d);
    float s2 = med3f(m3, h3, d);
    float s3 = fmaxf(h3, d);
    r1 = med3f(s0, s1, e);
    r2 = med3f(s1, s2, e);
    r3 = med3f(s2, s3, e);
}

__device__ __forceinline__ int reflect_idx(int i, int n) {
    if (i < 0) return -i;
    if (i >= n) return 2 * n - 2 - i;
    return i;
}

// Block = one image row; img = bid&7, y = bid>>3 (XCD-affine: each XCD owns
// one 4MB image == its L2; adjacent-y blocks dispatch consecutively on the
// same XCD, so each input row is fetched from HBM once).
// Median per window: shared sorted columns -> pruned row sorts (doubly
// monotone) -> 13 candidates in 5 poset chains -> chain merges + elementwise
// CE + rank pruning -> median-of-9 finisher. All identities are exact.
__global__ __launch_bounds__(256) void median_kernel(const float* __restrict__ in,
                                                     float* __restrict__ out) {
    const int bi  = blockIdx.x;
    const int img = bi & 7;
    const int y   = bi >> 3;
    const int tid = threadIdx.x;
    const int x0  = tid * 4;
    const float* base = in + (size_t)img * HH * WW;

    float patch[5][8];
    const bool interior = (tid != 0) && (tid != 255);
    #pragma unroll
    for (int r = 0; r < 5; r++) {
        const int yy = reflect_idx(y + r - 2, HH);
        const float* rp = base + (size_t)yy * WW;
        if (interior) {
            const float4 A = *reinterpret_cast<const float4*>(rp + x0 - 4);
            const float4 B = *reinterpret_cast<const float4*>(rp + x0);
            const float4 C = *reinterpret_cast<const float4*>(rp + x0 + 4);
            patch[r][0] = A.z; patch[r][1] = A.w;
            patch[r][2] = B.x; patch[r][3] = B.y;
            patch[r][4] = B.z; patch[r][5] = B.w;
            patch[r][6] = C.x; patch[r][7] = C.y;
        } else {
            #pragma unroll
            for (int c = 0; c < 8; c++) {
                const int xx = reflect_idx(x0 + c - 2, WW);
                patch[r][c] = rp[xx];
            }
        }
    }

    // Sort each of the 8 columns (shared by the 4 windows).
    #pragma unroll
    for (int c = 0; c < 8; c++) {
        sort5(patch[0][c], patch[1][c], patch[2][c], patch[3][c], patch[4][c]);
    }

    float med[4];
    #pragma unroll
    for (int j = 0; j < 4; j++) {
        // Pruned row sorts (rows = rank-i across the 5 sorted columns).
        // Row-sorting a column-sorted matrix keeps columns sorted (doubly
        // monotone); cell ranks prune to 13 median candidates:
        // row0 ranks {3,4}, row1 {2,3,4}, row2 {1,2,3}, row3 {0,1,2}, row4 {0,1}.
        float r03, r04, r12, r13, r14, r21, r22, r23, r30, r31, r32, r40, r41;
        top2(patch[0][j], patch[0][j+1], patch[0][j+2], patch[0][j+3], patch[0][j+4], r03, r04);
        top3(patch[1][j], patch[1][j+1], patch[1][j+2], patch[1][j+3], patch[1][j+4], r12, r13, r14);
        mid3(patch[2][j], patch[2][j+1], patch[2][j+2], patch[2][j+3], patch[2][j+4], r21, r22, r23);
        bot3(patch[3][j], patch[3][j+1], patch[3][j+2], patch[3][j+3], patch[3][j+4], r30, r31, r32);
        bot2(patch[4][j], patch[4][j+1], patch[4][j+2], patch[4][j+3], patch[4][j+4], r40, r41);

        // Poset chains (sorted, from row+column order):
        //   P: r30<=r31<=r32   S: r40<=r41  (with r30<=r40, r31<=r41, r40<=r41)
        //   Q: r21<=r22<=r23   T: r03<=r04  (with r03<=r23)
        //   Rc: r12<=r13<=r14
        // Merge P+S -> ps[5] (6 ops):
        float u = fminf(r40, r31), v = fmaxf(r40, r31);
        float w = fminf(v, r32),  x = fmaxf(v, r32);
        float ps0 = r30, ps1 = u, ps2 = w;
        float ps3 = fminf(x, r41), ps4 = fmaxf(x, r41);
        // Merge Q+T -> qt[5] (7 ops; uses r03<=r23 so top stays r23-capped):
        float q0 = fminf(r21, r03);
        float q1 = med3f(r21, r22, r03);
        float q2 = med3f(r22, r23, r03);
        float t1 = fminf(q1, r04);
        float t2 = med3f(q1, q2, r04);
        float t3 = med3f(q2, r23, r04);
        float t4 = fmaxf(r23, r04);
        // Elementwise CE of the two sorted 5-chains; rank pruning keeps only
        // X[2..4] (min side) and Y[0..2] (max side) as candidates (6 ops):
        float Y0 = fmaxf(ps0, q0);
        float Y1 = fmaxf(ps1, t1);
        float X2 = fminf(ps2, t2), Y2 = fmaxf(ps2, t2);
        float X3 = fminf(ps3, t3);
        float X4 = fminf(ps4, t4);
        // Median of 9 = med3(max3(mins), med3(meds), min3(maxs)) over the
        // three sorted triples (X2,X3,X4), (Y0,Y1,Y2), (r12,r13,r14) (4 ops):
        float L = max3f(X2, Y0, r12);
        float M = med3f(X3, Y1, r13);
        float H = min3f(X4, Y2, r14);
        med[j] = med3f(L, M, H);
    }

    float4 o;
    o.x = med[0]; o.y = med[1]; o.z = med[2]; o.w = med[3];
    *reinterpret_cast<float4*>(out + (size_t)img * HH * WW + (size_t)y * WW + x0) = o;
}

// Gaussian 5x5, zero padding, separable weights from runtime sigma.
// Same XCD-affine mapping: reads the median intermediate from the writer
// XCD's still-warm L2.
__global__ __launch_bounds__(256) void gauss_kernel(const float* __restrict__ in,
                                                    const float* __restrict__ sig,
                                                    float* __restrict__ out) {
    const int bi  = blockIdx.x;
    const int img = bi & 7;
    const int y   = bi >> 3;
    const int tid = threadIdx.x;
    const int x0  = tid * 4;

    const float sigma  = sig[0];
    const float inv2s2 = 1.0f / (2.0f * sigma * sigma);
    const float g1 = expf(-1.0f * inv2s2);
    const float g4 = expf(-4.0f * inv2s2);
    const float s  = 1.0f + 2.0f * g1 + 2.0f * g4;
    float wv[5];
    wv[0] = g4 / s; wv[1] = g1 / s; wv[2] = 1.0f / s; wv[3] = g1 / s; wv[4] = g4 / s;

    const float* base = in + (size_t)img * HH * WW;
    const bool interior = (tid != 0) && (tid != 255);

    float acc0 = 0.f, acc1 = 0.f, acc2 = 0.f, acc3 = 0.f;
    #pragma unroll
    for (int r = 0; r < 5; r++) {
        const int yy = y + r - 2;
        if (yy < 0 || yy >= HH) continue;  // zero padding
        const float* rp = base + (size_t)yy * WW;
        float row[8];
        if (interior) {
            const float4 A = *reinterpret_cast<const float4*>(rp + x0 - 4);
            const float4 B = *reinterpret_cast<const float4*>(rp + x0);
            const float4 C = *reinterpret_cast<const float4*>(rp + x0 + 4);
            row[0] = A.z; row[1] = A.w;
            row[2] = B.x; row[3] = B.y; row[4] = B.z; row[5] = B.w;
            row[6] = C.x; row[7] = C.y;
        } else {
            #pragma unroll
            for (int c = 0; c < 8; c++) {
                const int xx = x0 + c - 2;
                row[c] = (xx < 0 || xx >= WW) ? 0.0f : rp[xx];
            }
        }
        float h0 = 0.f, h1 = 0.f, h2 = 0.f, h3 = 0.f;
        #pragma unroll
        for (int c = 0; c < 5; c++) {
            h0 = fmaf(wv[c], row[0 + c], h0);
            h1 = fmaf(wv[c], row[1 + c], h1);
            h2 = fmaf(wv[c], row[2 + c], h2);
            h3 = fmaf(wv[c], row[3 + c], h3);
        }
        const float wy = wv[r];
        acc0 = fmaf(wy, h0, acc0);
        acc1 = fmaf(wy, h1, acc1);
        acc2 = fmaf(wy, h2, acc2);
        acc3 = fmaf(wy, h3, acc3);
    }

    float4 o;
    o.x = acc0; o.y = acc1; o.z = acc2; o.w = acc3;
    *reinterpret_cast<float4*>(out + (size_t)img * HH * WW + (size_t)y * WW + x0) = o;
}

extern "C" void kernel_launch(void* const* d_in, const int* in_sizes, int n_in,
                              void* d_out, int out_size, void* d_ws, size_t ws_size,
                              hipStream_t stream) {
    const float* img = (const float*)d_in[0];
    const float* sig = (const float*)d_in[1];
    float* med = (float*)d_ws;
    float* out = (float*)d_out;

    dim3 grid(NIMG * HH);
    dim3 block(256);
    hipLaunchKernelGGL(median_kernel, grid, block, 0, stream, img, med);
    hipLaunchKernelGGL(gauss_kernel, grid, block, 0, stream, med, sig, out);
}

// Round 4
// 43.115 us; speedup vs baseline: 2.4614x; 1.8161x over previous
//
#include <hip/hip_runtime.h>

#define HH 1024
#define WW 1024
#define NIMG 8
#define TROWS 16            // output rows per block
#define NSTEP (TROWS + 4)   // median rows per block (incl. +/-2 halo)

__device__ __forceinline__ float med3f(float a, float b, float c) {
    return __builtin_amdgcn_fmed3f(a, b, c);
}
__device__ __forceinline__ float min3f(float a, float b, float c) {
    return fminf(fminf(a, b), c);
}
__device__ __forceinline__ float max3f(float a, float b, float c) {
    return fmaxf(fmaxf(a, b), c);
}

// Full ascending sort5 (12 ops).
__device__ __forceinline__ void sort5(float& a, float& b, float& c, float& d, float& e) {
    float l3 = min3f(a, b, c);
    float m3 = med3f(a, b, c);
    float h3 = max3f(a, b, c);
    float s0 = fminf(l3, d);
    float s1 = med3f(l3, m3, d);
    float s2 = med3f(m3, h3, d);
    float s3 = fmaxf(h3, d);
    float r0 = fminf(s0, e);
    float r1 = med3f(s0, s1, e);
    float r2 = med3f(s1, s2, e);
    float r3 = med3f(s2, s3, e);
    float r4 = fmaxf(s3, e);
    a = r0; b = r1; c = r2; d = r3; e = r4;
}
// ranks 3,4 of 5
__device__ __forceinline__ void top2(float a, float b, float c, float d, float e,
                                     float& r3, float& r4) {
    float m3 = med3f(a, b, c);
    float h3 = max3f(a, b, c);
    float s2 = med3f(m3, h3, d);
    float s3 = fmaxf(h3, d);
    r3 = med3f(s2, s3, e);
    r4 = fmaxf(s3, e);
}
// ranks 0,1 of 5
__device__ __forceinline__ void bot2(float a, float b, float c, float d, float e,
                                     float& r0, float& r1) {
    float l3 = min3f(a, b, c);
    float m3 = med3f(a, b, c);
    float s0 = fminf(l3, d);
    float s1 = med3f(l3, m3, d);
    r0 = fminf(s0, e);
    r1 = med3f(s0, s1, e);
}
// ranks 2,3,4 of 5
__device__ __forceinline__ void top3(float a, float b, float c, float d, float e,
                                     float& r2, float& r3, float& r4) {
    float l3 = min3f(a, b, c);
    float m3 = med3f(a, b, c);
    float h3 = max3f(a, b, c);
    float s1 = med3f(l3, m3, d);
    float s2 = med3f(m3, h3, d);
    float s3 = fmaxf(h3, d);
    r2 = med3f(s1, s2, e);
    r3 = med3f(s2, s3, e);
    r4 = fmaxf(s3, e);
}
// ranks 0,1,2 of 5
__device__ __forceinline__ void bot3(float a, float b, float c, float d, float e,
                                     float& r0, float& r1, float& r2) {
    float l3 = min3f(a, b, c);
    float m3 = med3f(a, b, c);
    float h3 = max3f(a, b, c);
    float s0 = fminf(l3, d);
    float s1 = med3f(l3, m3, d);
    float s2 = med3f(m3, h3, d);
    r0 = fminf(s0, e);
    r1 = med3f(s0, s1, e);
    r2 = med3f(s1, s2, e);
}
// ranks 1,2,3 of 5
__device__ __forceinline__ void mid3(float a, float b, float c, float d, float e,
                                     float& r1, float& r2, float& r3) {
    float l3 = min3f(a, b, c);
    float m3 = med3f(a, b, c);
    float h3 = max3f(a, b, c);
    float s0 = fminf(l3, d);
    float s1 = med3f(l3, m3, d);
    float s2 = med3f(m3, h3, d);
    float s3 = fmaxf(h3, d);
    r1 = med3f(s0, s1, e);
    r2 = med3f(s1, s2, e);
    r3 = med3f(s2, s3, e);
}

struct Row8 { float v[8]; };

// Fused median(reflect) + gaussian(zero-pad) row-walking kernel.
// Block = 16 output rows x 1024 wide. img = bid&7 -> XCD-affine.
// Per step: prefetch 1 input row (ring of 6), median row m via sorted-column
// network, x-halo exchange of the median row through double-buffered LDS
// (1 barrier/step), horizontal gauss, 6-slot h-ring, vertical gauss + store.
__global__ __launch_bounds__(256, 2) void fused_kernel(const float* __restrict__ in,
                                                       const float* __restrict__ sig,
                                                       float* __restrict__ out) {
    const int bi   = blockIdx.x;
    const int img  = bi & 7;
    const int tile = bi >> 3;
    const int y0   = tile * TROWS;
    const int tid  = threadIdx.x;
    const int x0   = tid * 4;
    const float* base  = in  + (size_t)img * HH * WW;
    float*       obase = out + (size_t)img * HH * WW;

    // Gaussian weights (separable; (sum g)^2 normalization == reference)
    const float sigma  = sig[0];
    const float inv2s2 = 1.0f / (2.0f * sigma * sigma);
    const float g1 = expf(-1.0f * inv2s2);
    const float g4 = expf(-4.0f * inv2s2);
    const float sn = 1.0f + 2.0f * g1 + 2.0f * g4;
    float wv[5];
    wv[0] = g4 / sn; wv[1] = g1 / sn; wv[2] = 1.0f / sn; wv[3] = g1 / sn; wv[4] = g4 / sn;

    // double-buffered median-row exchange line, 2-col zero borders for x zero-pad
    __shared__ float lbuf[2][WW + 4];
    if (tid < 2) {
        lbuf[tid][0] = 0.f; lbuf[tid][1] = 0.f;
        lbuf[tid][WW + 2] = 0.f; lbuf[tid][WW + 3] = 0.f;
    }

    Row8  ring[6];   // raw input rows (reflected), slot = (row - y0 + 4) mod 6
    float hr[6][4];  // horizontally-blurred median rows, slot = step mod 6

    // load one reflect-padded input row; x edges fixed branchlessly
    auto loadrow = [&](int r) -> Row8 {
        const int rr = (r < 0) ? -r : (r >= HH ? 2 * HH - 2 - r : r);
        const float* rp = base + (size_t)rr * WW;
        const float4 A = *reinterpret_cast<const float4*>(rp + (tid == 0   ? x0 : x0 - 4));
        const float4 B = *reinterpret_cast<const float4*>(rp + x0);
        const float4 C = *reinterpret_cast<const float4*>(rp + (tid == 255 ? x0 : x0 + 4));
        Row8 d;
        d.v[0] = (tid == 0)   ? B.z : A.z;   // reflect(-2)=2, reflect(-1)=1
        d.v[1] = (tid == 0)   ? B.y : A.w;
        d.v[2] = B.x; d.v[3] = B.y; d.v[4] = B.z; d.v[5] = B.w;
        d.v[6] = (tid == 255) ? B.z : C.x;   // reflect(1024)=1022, reflect(1025)=1021
        d.v[7] = (tid == 255) ? B.y : C.y;
        return d;
    };

    // prime ring with rows y0-4 .. y0 (slots 0..4)
    #pragma unroll
    for (int k = 0; k < 5; ++k) ring[k] = loadrow(y0 - 4 + k);

    __syncthreads();  // cover border zero init

    for (int outer = 0; outer < 4; ++outer) {
        #pragma unroll
        for (int p = 0; p < 6; ++p) {
            const int s = outer * 6 + p;
            if (s < NSTEP) {
                // prefetch next input row into the free slot (one step ahead)
                if (s + 1 < NSTEP) ring[(p + 5) % 6] = loadrow(y0 + s + 1);

                const int m = y0 - 2 + s;  // median row this step
                float med0 = 0.f, med1 = 0.f, med2 = 0.f, med3v = 0.f;
                if (m >= 0 && m < HH) {
                    // sort the 8 columns of the 5-row window (slots p..p+4)
                    float S0[8], S1[8], S2[8], S3[8], S4[8];
                    #pragma unroll
                    for (int c = 0; c < 8; ++c) {
                        float a = ring[p].v[c];
                        float b = ring[(p + 1) % 6].v[c];
                        float g = ring[(p + 2) % 6].v[c];
                        float d = ring[(p + 3) % 6].v[c];
                        float e = ring[(p + 4) % 6].v[c];
                        sort5(a, b, g, d, e);
                        S0[c] = a; S1[c] = b; S2[c] = g; S3[c] = d; S4[c] = e;
                    }
                    float med[4];
                    #pragma unroll
                    for (int j = 0; j < 4; ++j) {
                        // pruned row sorts of the doubly-monotone 5x5
                        float r03, r04, r12, r13, r14, r21, r22, r23, r30, r31, r32, r40, r41;
                        top2(S0[j], S0[j+1], S0[j+2], S0[j+3], S0[j+4], r03, r04);
                        top3(S1[j], S1[j+1], S1[j+2], S1[j+3], S1[j+4], r12, r13, r14);
                        mid3(S2[j], S2[j+1], S2[j+2], S2[j+3], S2[j+4], r21, r22, r23);
                        bot3(S3[j], S3[j+1], S3[j+2], S3[j+3], S3[j+4], r30, r31, r32);
                        bot2(S4[j], S4[j+1], S4[j+2], S4[j+3], S4[j+4], r40, r41);
                        // chain merges + elementwise CE + median-of-9 (exact)
                        float u = fminf(r40, r31), v = fmaxf(r40, r31);
                        float w = fminf(v, r32),  x = fmaxf(v, r32);
                        float ps0 = r30, ps1 = u, ps2 = w;
                        float ps3 = fminf(x, r41), ps4 = fmaxf(x, r41);
                        float q0 = fminf(r21, r03);
                        float q1 = med3f(r21, r22, r03);
                        float q2 = med3f(r22, r23, r03);
                        float t1 = fminf(q1, r04);
                        float t2 = med3f(q1, q2, r04);
                        float t3 = med3f(q2, r23, r04);
                        float t4 = fmaxf(r23, r04);
                        float Y0 = fmaxf(ps0, q0);
                        float Y1 = fmaxf(ps1, t1);
                        float X2 = fminf(ps2, t2), Y2 = fmaxf(ps2, t2);
                        float X3 = fminf(ps3, t3);
                        float X4 = fminf(ps4, t4);
                        float L = max3f(X2, Y0, r12);
                        float M = med3f(X3, Y1, r13);
                        float Hc = min3f(X4, Y2, r14);
                        med[j] = med3f(L, M, Hc);
                    }
                    med0 = med[0]; med1 = med[1]; med2 = med[2]; med3v = med[3];
                }

                // x-halo exchange of the median row (zero rows pass zeros)
                float* Lb = lbuf[p & 1];
                Lb[x0 + 2] = med0; Lb[x0 + 3] = med1;
                Lb[x0 + 4] = med2; Lb[x0 + 5] = med3v;
                __syncthreads();
                const float4 Ha = *reinterpret_cast<const float4*>(&Lb[x0]);
                const float4 Hb = *reinterpret_cast<const float4*>(&Lb[x0 + 4]);
                float hh[8] = { Ha.x, Ha.y, Ha.z, Ha.w, Hb.x, Hb.y, Hb.z, Hb.w };

                // horizontal gauss -> h-ring slot p
                #pragma unroll
                for (int j = 0; j < 4; ++j) {
                    float h = 0.f;
                    #pragma unroll
                    for (int c = 0; c < 5; ++c) h = fmaf(wv[c], hh[j + c], h);
                    hr[p][j] = h;
                }

                // vertical gauss + store (output row o = y0 + s - 4)
                if (s >= 4) {
                    const int o = y0 + s - 4;
                    float4 ov;
                    float a0 = 0.f, a1 = 0.f, a2 = 0.f, a3 = 0.f;
                    #pragma unroll
                    for (int k = 0; k < 5; ++k) {
                        const float wy = wv[k];
                        const int sl = (p + 2 + k) % 6;  // h of median row o-2+k
                        a0 = fmaf(wy, hr[sl][0], a0);
                        a1 = fmaf(wy, hr[sl][1], a1);
                        a2 = fmaf(wy, hr[sl][2], a2);
                        a3 = fmaf(wy, hr[sl][3], a3);
                    }
                    ov.x = a0; ov.y = a1; ov.z = a2; ov.w = a3;
                    *reinterpret_cast<float4*>(obase + (size_t)o * WW + x0) = ov;
                }
            }
        }
    }
}

extern "C" void kernel_launch(void* const* d_in, const int* in_sizes, int n_in,
                              void* d_out, int out_size, void* d_ws, size_t ws_size,
                              hipStream_t stream) {
    const float* img = (const float*)d_in[0];
    const float* sig = (const float*)d_in[1];
    float* out = (float*)d_out;

    dim3 grid(NIMG * (HH / TROWS));  // 512 blocks, XCD-affine via bid&7
    dim3 block(256);
    hipLaunchKernelGGL(fused_kernel, grid, block, 0, stream, img, sig, out);
}

// Round 5
// 39.220 us; speedup vs baseline: 2.7058x; 1.0993x over previous
//
#include <hip/hip_runtime.h>

#define HH 1024
#define WW 1024
#define NIMG 8
#define TROWS 16            // output rows per block
#define NSTEP (TROWS + 4)   // 20 median rows per block (incl. +/-2 halo)

__device__ __forceinline__ float med3f(float a, float b, float c) {
    return __builtin_amdgcn_fmed3f(a, b, c);
}
__device__ __forceinline__ float min3f(float a, float b, float c) {
    return fminf(fminf(a, b), c);
}
__device__ __forceinline__ float max3f(float a, float b, float c) {
    return fmaxf(fmaxf(a, b), c);
}

// Full ascending sort5 (12 ops).
__device__ __forceinline__ void sort5(float& a, float& b, float& c, float& d, float& e) {
    float l3 = min3f(a, b, c);
    float m3 = med3f(a, b, c);
    float h3 = max3f(a, b, c);
    float s0 = fminf(l3, d);
    float s1 = med3f(l3, m3, d);
    float s2 = med3f(m3, h3, d);
    float s3 = fmaxf(h3, d);
    float r0 = fminf(s0, e);
    float r1 = med3f(s0, s1, e);
    float r2 = med3f(s1, s2, e);
    float r3 = med3f(s2, s3, e);
    float r4 = fmaxf(s3, e);
    a = r0; b = r1; c = r2; d = r3; e = r4;
}
// ranks 3,4 of 5
__device__ __forceinline__ void top2(float a, float b, float c, float d, float e,
                                     float& r3, float& r4) {
    float m3 = med3f(a, b, c);
    float h3 = max3f(a, b, c);
    float s2 = med3f(m3, h3, d);
    float s3 = fmaxf(h3, d);
    r3 = med3f(s2, s3, e);
    r4 = fmaxf(s3, e);
}
// ranks 0,1 of 5
__device__ __forceinline__ void bot2(float a, float b, float c, float d, float e,
                                     float& r0, float& r1) {
    float l3 = min3f(a, b, c);
    float m3 = med3f(a, b, c);
    float s0 = fminf(l3, d);
    float s1 = med3f(l3, m3, d);
    r0 = fminf(s0, e);
    r1 = med3f(s0, s1, e);
}
// ranks 2,3,4 of 5
__device__ __forceinline__ void top3(float a, float b, float c, float d, float e,
                                     float& r2, float& r3, float& r4) {
    float l3 = min3f(a, b, c);
    float m3 = med3f(a, b, c);
    float h3 = max3f(a, b, c);
    float s1 = med3f(l3, m3, d);
    float s2 = med3f(m3, h3, d);
    float s3 = fmaxf(h3, d);
    r2 = med3f(s1, s2, e);
    r3 = med3f(s2, s3, e);
    r4 = fmaxf(s3, e);
}
// ranks 0,1,2 of 5
__device__ __forceinline__ void bot3(float a, float b, float c, float d, float e,
                                     float& r0, float& r1, float& r2) {
    float l3 = min3f(a, b, c);
    float m3 = med3f(a, b, c);
    float h3 = max3f(a, b, c);
    float s0 = fminf(l3, d);
    float s1 = med3f(l3, m3, d);
    float s2 = med3f(m3, h3, d);
    r0 = fminf(s0, e);
    r1 = med3f(s0, s1, e);
    r2 = med3f(s1, s2, e);
}
// ranks 1,2,3 of 5
__device__ __forceinline__ void mid3(float a, float b, float c, float d, float e,
                                     float& r1, float& r2, float& r3) {
    float l3 = min3f(a, b, c);
    float m3 = med3f(a, b, c);
    float h3 = max3f(a, b, c);
    float s0 = fminf(l3, d);
    float s1 = med3f(l3, m3, d);
    float s2 = med3f(m3, h3, d);
    float s3 = fmaxf(h3, d);
    r1 = med3f(s0, s1, e);
    r2 = med3f(s1, s2, e);
    r3 = med3f(s2, s3, e);
}

// load one reflect-padded input row (x handled branchlessly per-lane)
__device__ __forceinline__ void loadrow(const float* __restrict__ base, int r,
                                        int tid, int x0, float (&d)[8]) {
    const int rr = (r < 0) ? -r : (r >= HH ? 2 * HH - 2 - r : r);
    const float* rp = base + (size_t)rr * WW;
    const float4 A = *reinterpret_cast<const float4*>(rp + (tid == 0   ? x0 : x0 - 4));
    const float4 B = *reinterpret_cast<const float4*>(rp + x0);
    const float4 C = *reinterpret_cast<const float4*>(rp + (tid == 255 ? x0 : x0 + 4));
    d[0] = (tid == 0)   ? B.z : A.z;   // reflect(-2)=2, reflect(-1)=1
    d[1] = (tid == 0)   ? B.y : A.w;
    d[2] = B.x; d[3] = B.y; d[4] = B.z; d[5] = B.w;
    d[6] = (tid == 255) ? B.z : C.x;   // reflect(1024)=1022, reflect(1025)=1021
    d[7] = (tid == 255) ? B.y : C.y;
}

// 13-candidate exact median network over ring slots (P..P+4)%6 (verified R2-R4)
template<int P>
__device__ __forceinline__ void median4(const float (&ring)[6][8], float (&med)[4]) {
    float S0[8], S1[8], S2[8], S3[8], S4[8];
    #pragma unroll
    for (int c = 0; c < 8; ++c) {
        float a = ring[P % 6][c];
        float b = ring[(P + 1) % 6][c];
        float g = ring[(P + 2) % 6][c];
        float d = ring[(P + 3) % 6][c];
        float e = ring[(P + 4) % 6][c];
        sort5(a, b, g, d, e);
        S0[c] = a; S1[c] = b; S2[c] = g; S3[c] = d; S4[c] = e;
    }
    #pragma unroll
    for (int j = 0; j < 4; ++j) {
        float r03, r04, r12, r13, r14, r21, r22, r23, r30, r31, r32, r40, r41;
        top2(S0[j], S0[j+1], S0[j+2], S0[j+3], S0[j+4], r03, r04);
        top3(S1[j], S1[j+1], S1[j+2], S1[j+3], S1[j+4], r12, r13, r14);
        mid3(S2[j], S2[j+1], S2[j+2], S2[j+3], S2[j+4], r21, r22, r23);
        bot3(S3[j], S3[j+1], S3[j+2], S3[j+3], S3[j+4], r30, r31, r32);
        bot2(S4[j], S4[j+1], S4[j+2], S4[j+3], S4[j+4], r40, r41);
        float u = fminf(r40, r31), v = fmaxf(r40, r31);
        float w = fminf(v, r32),  x = fmaxf(v, r32);
        float ps0 = r30, ps1 = u, ps2 = w;
        float ps3 = fminf(x, r41), ps4 = fmaxf(x, r41);
        float q0 = fminf(r21, r03);
        float q1 = med3f(r21, r22, r03);
        float q2 = med3f(r22, r23, r03);
        float t1 = fminf(q1, r04);
        float t2 = med3f(q1, q2, r04);
        float t3 = med3f(q2, r23, r04);
        float t4 = fmaxf(r23, r04);
        float Y0 = fmaxf(ps0, q0);
        float Y1 = fmaxf(ps1, t1);
        float X2 = fminf(ps2, t2), Y2 = fmaxf(ps2, t2);
        float X3 = fminf(ps3, t3);
        float X4 = fminf(ps4, t4);
        float L  = max3f(X2, Y0, r12);
        float M  = med3f(X3, Y1, r13);
        float Hc = min3f(X4, Y2, r14);
        med[j] = med3f(L, M, Hc);
    }
}

// One pipeline step, P = s % 6 (template -> all ring/hr indices static).
// Order: issue lbuf read (lagged, for s-1) + global prefetch early; median
// compute in between hides their latency; barrier at END of step.
// 2 LDS buffers safe: reader of slot s%2 (step s+1) drains before writer
// (step s+2) crosses barrier_{s+1}.
template<int P>
__device__ __forceinline__ void step(int s, int y0, int tid, int x0,
                                     const float* __restrict__ base,
                                     float* __restrict__ obase,
                                     const float (&wv)[5],
                                     float (&ring)[6][8], float (&hr)[6][4],
                                     float (*lbuf)[1040]) {
    // lagged halo read for med row s-1 (written last step, synced by barrier)
    float hh[8];
    if (s >= 1) {
        const float* Lb = lbuf[(s + 1) & 1];
        const float4 Ha = *reinterpret_cast<const float4*>(&Lb[x0]);
        const float4 Hb = *reinterpret_cast<const float4*>(&Lb[x0 + 4]);
        hh[0] = Ha.x; hh[1] = Ha.y; hh[2] = Ha.z; hh[3] = Ha.w;
        hh[4] = Hb.x; hh[5] = Hb.y; hh[6] = Hb.z; hh[7] = Hb.w;
    }
    // prefetch next input row (consumed next step)
    if (s < NSTEP - 1) loadrow(base, y0 + s + 1, tid, x0, ring[(P + 5) % 6]);

    // median row index m = y0 - 2 + s; zero outside [0,HH) (gauss zero-pad)
    float med[4] = {0.f, 0.f, 0.f, 0.f};
    const int m = y0 - 2 + s;
    if (s < NSTEP && m >= 0 && m < HH) median4<P>(ring, med);

    if (s < NSTEP) {
        float* Lw = lbuf[s & 1];
        *reinterpret_cast<float2*>(&Lw[x0 + 2]) = make_float2(med[0], med[1]);
        *reinterpret_cast<float2*>(&Lw[x0 + 4]) = make_float2(med[2], med[3]);
    }

    // horizontal gauss for med row s-1 -> hr slot (s-1)%6 = (P+5)%6
    if (s >= 1) {
        #pragma unroll
        for (int j = 0; j < 4; ++j) {
            float h = 0.f;
            #pragma unroll
            for (int c = 0; c < 5; ++c) h = fmaf(wv[c], hh[j + c], h);
            hr[(P + 5) % 6][j] = h;
        }
    }

    // vertical gauss + store output row o = y0 + s - 5
    if (s >= 5) {
        const int o = y0 + s - 5;
        float a0 = 0.f, a1 = 0.f, a2 = 0.f, a3 = 0.f;
        #pragma unroll
        for (int k = 0; k < 5; ++k) {
            const int   sl = (P + 1 + k) % 6;  // h of med row (s-5+k)
            const float wy = wv[k];
            a0 = fmaf(wy, hr[sl][0], a0);
            a1 = fmaf(wy, hr[sl][1], a1);
            a2 = fmaf(wy, hr[sl][2], a2);
            a3 = fmaf(wy, hr[sl][3], a3);
        }
        *reinterpret_cast<float4*>(obase + (size_t)o * WW + x0) =
            make_float4(a0, a1, a2, a3);
    }
    __syncthreads();
}

// Fused median(reflect) + gaussian(zero-pad). Block = 16 rows x 1024 px.
// img = bid & 7 -> XCD-affine (each image lives in one XCD's 4MB L2).
__global__ __launch_bounds__(256, 2) void fused_kernel(const float* __restrict__ in,
                                                       const float* __restrict__ sig,
                                                       float* __restrict__ out) {
    const int bi   = blockIdx.x;
    const int img  = bi & 7;
    const int tile = bi >> 3;
    const int y0   = tile * TROWS;
    const int tid  = threadIdx.x;
    const int x0   = tid * 4;
    const float* base  = in  + (size_t)img * HH * WW;
    float*       obase = out + (size_t)img * HH * WW;

    const float sigma  = sig[0];
    const float inv2s2 = 1.0f / (2.0f * sigma * sigma);
    const float g1 = expf(-1.0f * inv2s2);
    const float g4 = expf(-4.0f * inv2s2);
    const float sn = 1.0f + 2.0f * g1 + 2.0f * g4;
    const float wv[5] = { g4 / sn, g1 / sn, 1.0f / sn, g1 / sn, g4 / sn };

    // double-buffered exchange rows; [0,1] and [1026,1027] are zero borders;
    // row stride 1040 keeps both buffers 16B-aligned.
    __shared__ float lbuf[2][1040];
    if (tid < 2) {
        lbuf[tid][0] = 0.f; lbuf[tid][1] = 0.f;
        lbuf[tid][1026] = 0.f; lbuf[tid][1027] = 0.f;
    }

    float ring[6][8];   // input rows; row y0+t <-> slot (t+4)%6
    float hr[6][4];     // h-blurred med rows; med row j <-> slot j%6

    #pragma unroll
    for (int k = 0; k < 5; ++k) loadrow(base, y0 - 4 + k, tid, x0, ring[k]);

    // s = 0..17 : 3 x 6 statically-instantiated phases
    for (int outer = 0; outer < 3; ++outer) {
        const int sb = outer * 6;
        step<0>(sb + 0, y0, tid, x0, base, obase, wv, ring, hr, lbuf);
        step<1>(sb + 1, y0, tid, x0, base, obase, wv, ring, hr, lbuf);
        step<2>(sb + 2, y0, tid, x0, base, obase, wv, ring, hr, lbuf);
        step<3>(sb + 3, y0, tid, x0, base, obase, wv, ring, hr, lbuf);
        step<4>(sb + 4, y0, tid, x0, base, obase, wv, ring, hr, lbuf);
        step<5>(sb + 5, y0, tid, x0, base, obase, wv, ring, hr, lbuf);
    }
    // tail: s = 18, 19, 20 (drain: last h + last 3 outputs)
    step<0>(18, y0, tid, x0, base, obase, wv, ring, hr, lbuf);
    step<1>(19, y0, tid, x0, base, obase, wv, ring, hr, lbuf);
    step<2>(20, y0, tid, x0, base, obase, wv, ring, hr, lbuf);
}

extern "C" void kernel_launch(void* const* d_in, const int* in_sizes, int n_in,
                              void* d_out, int out_size, void* d_ws, size_t ws_size,
                              hipStream_t stream) {
    const float* img = (const float*)d_in[0];
    const float* sig = (const float*)d_in[1];
    float* out = (float*)d_out;

    dim3 grid(NIMG * (HH / TROWS));  // 512 blocks, XCD-affine via bid&7
    dim3 block(256);
    hipLaunchKernelGGL(fused_kernel, grid, block, 0, stream, img, sig, out);
}